// Round 1
// baseline (1293.991 us; speedup 1.0000x reference)
//
#include <hip/hip_runtime.h>
#include <hip/hip_bf16.h>

#define SQ   4096
#define HIDN 2048
#define NH   16
#define NKV  8
#define HD   128
#define QD   2048   // NH*HD
#define KD   1024   // NKV*HD

typedef __bf16 bf16x8 __attribute__((ext_vector_type(8)));
typedef float  f32x4  __attribute__((ext_vector_type(4)));

__device__ __forceinline__ float b2f(unsigned short u) {
    union { float f; unsigned int i; } v; v.i = ((unsigned int)u) << 16; return v.f;
}
__device__ __forceinline__ unsigned short f2b(float f) {
    union { float f; unsigned int i; } v; v.f = f;
    unsigned int i = v.i;
    return (unsigned short)((i + 0x7FFFu + ((i >> 16) & 1u)) >> 16);
}

__device__ __forceinline__ void gload_lds16(const void* g, void* l) {
    __builtin_amdgcn_global_load_lds(
        (const __attribute__((address_space(1))) unsigned int*)g,
        (__attribute__((address_space(3))) unsigned int*)l, 16, 0, 0);
}

#define MFMA16(a, b, c) __builtin_amdgcn_mfma_f32_16x16x32_bf16(a, b, c, 0, 0, 0)

// ---------------------------------------------------------------------------
// f32 -> bf16 convert (vectorized)
// ---------------------------------------------------------------------------
__global__ __launch_bounds__(256) void cvt_f32_bf16(const float* __restrict__ in,
                                                    unsigned short* __restrict__ out,
                                                    int n4) {
    int i = blockIdx.x * 256 + threadIdx.x;
    if (i < n4) {
        float4 v = ((const float4*)in)[i];
        ushort4 u;
        u.x = f2b(v.x); u.y = f2b(v.y); u.z = f2b(v.z); u.w = f2b(v.w);
        ((ushort4*)out)[i] = u;
    }
}

// ---------------------------------------------------------------------------
// RoPE cos/sin table: [S][64] each
// ---------------------------------------------------------------------------
__global__ __launch_bounds__(256) void rope_table(const int* __restrict__ pos,
                                                  float* __restrict__ cosT,
                                                  float* __restrict__ sinT) {
    int i = blockIdx.x * 256 + threadIdx.x;  // S*64 total
    int s = i >> 6, j = i & 63;
    double invf = exp(-(double)j * (log(1.0e6) / 64.0));
    float a = (float)((double)pos[s] * invf);
    cosT[i] = cosf(a);
    sinT[i] = sinf(a);
}

// ---------------------------------------------------------------------------
// GEMM: C[M][N] = A[M][K] @ B[N][K]^T + bias   (A,B bf16; 128x128 tile)
// EPI 0: bf16 row-major   EPI 1: f32 row-major   EPI 2: bf16 transposed C[N][M]
// ---------------------------------------------------------------------------
template <int EPI>
__global__ __launch_bounds__(256) void gemm128(const unsigned short* __restrict__ A,
                                               const unsigned short* __restrict__ B,
                                               const float* __restrict__ bias,
                                               void* __restrict__ Cout,
                                               int M, int N, int K) {
    __shared__ unsigned short As[128 * 32];
    __shared__ unsigned short Bs[128 * 32];
    const int tid = threadIdx.x, wid = tid >> 6, lane = tid & 63;
    const int g = lane >> 4, c = lane & 15;
    const int wr = wid >> 1, wc = wid & 1;
    const long rowbase = (long)blockIdx.y * 128;
    const long colbase = (long)blockIdx.x * 128;

    f32x4 acc[4][4];
#pragma unroll
    for (int m = 0; m < 4; ++m)
#pragma unroll
        for (int n = 0; n < 4; ++n) acc[m][n] = (f32x4){0.f, 0.f, 0.f, 0.f};

    const int ch0 = (wid * 2) * 64 + lane;
    const int ch1 = (wid * 2 + 1) * 64 + lane;

    for (int kt = 0; kt < K; kt += 32) {
        gload_lds16(A + ((rowbase + (ch0 >> 2)) * K + kt + (ch0 & 3) * 8),
                    As + (wid * 2) * 64 * 8);
        gload_lds16(B + ((colbase + (ch0 >> 2)) * K + kt + (ch0 & 3) * 8),
                    Bs + (wid * 2) * 64 * 8);
        gload_lds16(A + ((rowbase + (ch1 >> 2)) * K + kt + (ch1 & 3) * 8),
                    As + (wid * 2 + 1) * 64 * 8);
        gload_lds16(B + ((colbase + (ch1 >> 2)) * K + kt + (ch1 & 3) * 8),
                    Bs + (wid * 2 + 1) * 64 * 8);
        __syncthreads();
        bf16x8 a[4], b[4];
#pragma unroll
        for (int m = 0; m < 4; ++m)
            a[m] = *(const bf16x8*)(As + (wr * 64 + m * 16 + c) * 32 + g * 8);
#pragma unroll
        for (int n = 0; n < 4; ++n)
            b[n] = *(const bf16x8*)(Bs + (wc * 64 + n * 16 + c) * 32 + g * 8);
#pragma unroll
        for (int m = 0; m < 4; ++m)
#pragma unroll
            for (int n = 0; n < 4; ++n) acc[m][n] = MFMA16(a[m], b[n], acc[m][n]);
        __syncthreads();
    }

#pragma unroll
    for (int m = 0; m < 4; ++m) {
        const long grow0 = rowbase + wr * 64 + m * 16 + g * 4;
#pragma unroll
        for (int n = 0; n < 4; ++n) {
            const long gcol = colbase + wc * 64 + n * 16 + c;
            const float bs = bias[gcol];
            if (EPI == 0) {
                unsigned short* C = (unsigned short*)Cout;
#pragma unroll
                for (int r = 0; r < 4; ++r)
                    C[(grow0 + r) * N + gcol] = f2b(acc[m][n][r] + bs);
            } else if (EPI == 1) {
                float* C = (float*)Cout;
#pragma unroll
                for (int r = 0; r < 4; ++r)
                    C[(grow0 + r) * N + gcol] = acc[m][n][r] + bs;
            } else {
                unsigned short* C = (unsigned short*)Cout;
                ushort4 pk;
                pk.x = f2b(acc[m][n][0] + bs);
                pk.y = f2b(acc[m][n][1] + bs);
                pk.z = f2b(acc[m][n][2] + bs);
                pk.w = f2b(acc[m][n][3] + bs);
                *(ushort4*)(C + gcol * (long)M + grow0) = pk;
            }
        }
    }
}

// ---------------------------------------------------------------------------
// RMSNorm + RoPE + transpose to head-major [nh][S][HD]; one wave per (s,h)
// ---------------------------------------------------------------------------
__global__ __launch_bounds__(256) void norm_rope(const unsigned short* __restrict__ proj,
                                                 int nh,
                                                 const float* __restrict__ w,
                                                 const float* __restrict__ cosT,
                                                 const float* __restrict__ sinT,
                                                 unsigned short* __restrict__ outt,
                                                 float oscale) {
    int wv = (blockIdx.x * 256 + threadIdx.x) >> 6;  // over S*nh
    int lane = threadIdx.x & 63;
    int s = wv / nh, h = wv - s * nh;
    const unsigned short* p = proj + (size_t)s * (nh * HD) + h * HD;
    float x1 = b2f(p[lane]);
    float x2 = b2f(p[lane + 64]);
    float ss = x1 * x1 + x2 * x2;
#pragma unroll
    for (int d = 1; d < 64; d <<= 1) ss += __shfl_xor(ss, d);
    float r = rsqrtf(ss * (1.f / 128.f) + 1e-6f);
    x1 *= r * w[lane];
    x2 *= r * w[lane + 64];
    float cs = cosT[s * 64 + lane], sn = sinT[s * 64 + lane];
    unsigned short o1 = f2b((x1 * cs - x2 * sn) * oscale);
    unsigned short o2 = f2b((x2 * cs + x1 * sn) * oscale);
    unsigned short* q = outt + ((size_t)h * SQ + s) * HD;
    q[lane] = o1;
    q[lane + 64] = o2;
}

// ---------------------------------------------------------------------------
// Causal flash attention.
// qt: [NH][S][HD] (pre-scaled), kt: [NKV][S][HD], vt: [NKV][HD][S] (d-major)
// aout: [S][QD] bf16.  Grid (S/128, NH), 4 waves, 32 q-rows per wave, KV tile 64.
// ---------------------------------------------------------------------------
__global__ __launch_bounds__(256) void fattn(const unsigned short* __restrict__ qt,
                                             const unsigned short* __restrict__ kt,
                                             const unsigned short* __restrict__ vt,
                                             unsigned short* __restrict__ aout) {
    __shared__ unsigned short Pl[4][32][72];  // padded: no bank conflict on writes
    const int tid = threadIdx.x, wid = tid >> 6, lane = tid & 63;
    const int g = lane >> 4, c = lane & 15;
    const int h = blockIdx.y, hk = h >> 1;
    const int qb = gridDim.x - 1 - blockIdx.x;  // longest blocks first
    const int qrow0 = qb * 128 + wid * 32;
    const unsigned short* qh = qt + (size_t)h * SQ * HD;
    const unsigned short* kh = kt + (size_t)hk * SQ * HD;
    const unsigned short* vh = vt + (size_t)hk * HD * SQ;

    bf16x8 qa[2][4];
#pragma unroll
    for (int m = 0; m < 2; ++m)
#pragma unroll
        for (int ks = 0; ks < 4; ++ks)
            qa[m][ks] = *(const bf16x8*)(qh + (size_t)(qrow0 + m * 16 + c) * HD + ks * 32 + g * 8);

    f32x4 o[2][8];
#pragma unroll
    for (int m = 0; m < 2; ++m)
#pragma unroll
        for (int df = 0; df < 8; ++df) o[m][df] = (f32x4){0.f, 0.f, 0.f, 0.f};
    float mrow[2][4], lrow[2][4];
#pragma unroll
    for (int m = 0; m < 2; ++m)
#pragma unroll
        for (int r = 0; r < 4; ++r) { mrow[m][r] = -1e30f; lrow[m][r] = 0.f; }

    const int nkv = (qrow0 + 32 + 63) >> 6;
    for (int j = 0; j < nkv; ++j) {
        const int kv0 = j * 64;
        f32x4 sa[2][4];
#pragma unroll
        for (int m = 0; m < 2; ++m)
#pragma unroll
            for (int nf = 0; nf < 4; ++nf) sa[m][nf] = (f32x4){0.f, 0.f, 0.f, 0.f};
#pragma unroll
        for (int nf = 0; nf < 4; ++nf) {
            bf16x8 kf[4];
#pragma unroll
            for (int ks = 0; ks < 4; ++ks)
                kf[ks] = *(const bf16x8*)(kh + (size_t)(kv0 + nf * 16 + c) * HD + ks * 32 + g * 8);
#pragma unroll
            for (int ks = 0; ks < 4; ++ks) {
                sa[0][nf] = MFMA16(qa[0][ks], kf[ks], sa[0][nf]);
                sa[1][nf] = MFMA16(qa[1][ks], kf[ks], sa[1][nf]);
            }
        }
        if (kv0 + 63 > qrow0) {  // causal mask needed
#pragma unroll
            for (int m = 0; m < 2; ++m)
#pragma unroll
                for (int nf = 0; nf < 4; ++nf)
#pragma unroll
                    for (int r = 0; r < 4; ++r) {
                        int row = qrow0 + m * 16 + g * 4 + r;
                        int col = kv0 + nf * 16 + c;
                        if (col > row) sa[m][nf][r] = -1e30f;
                    }
        }
        float psc[2][4];
#pragma unroll
        for (int m = 0; m < 2; ++m)
#pragma unroll
            for (int r = 0; r < 4; ++r) {
                float mx = fmaxf(fmaxf(sa[m][0][r], sa[m][1][r]),
                                 fmaxf(sa[m][2][r], sa[m][3][r]));
                mx = fmaxf(mx, __shfl_xor(mx, 1));
                mx = fmaxf(mx, __shfl_xor(mx, 2));
                mx = fmaxf(mx, __shfl_xor(mx, 4));
                mx = fmaxf(mx, __shfl_xor(mx, 8));
                float mn = fmaxf(mrow[m][r], mx);
                float sc = __expf(mrow[m][r] - mn);
                mrow[m][r] = mn;
                float rs = 0.f;
#pragma unroll
                for (int nf = 0; nf < 4; ++nf) {
                    float p = __expf(sa[m][nf][r] - mn);
                    sa[m][nf][r] = p;
                    rs += p;
                }
                rs += __shfl_xor(rs, 1);
                rs += __shfl_xor(rs, 2);
                rs += __shfl_xor(rs, 4);
                rs += __shfl_xor(rs, 8);
                lrow[m][r] = lrow[m][r] * sc + rs;
                psc[m][r] = sc;
            }
#pragma unroll
        for (int m = 0; m < 2; ++m)
#pragma unroll
            for (int df = 0; df < 8; ++df)
#pragma unroll
                for (int r = 0; r < 4; ++r) o[m][df][r] *= psc[m][r];
        // P -> LDS (bf16), re-layout for PV A-operand
#pragma unroll
        for (int m = 0; m < 2; ++m)
#pragma unroll
            for (int nf = 0; nf < 4; ++nf)
#pragma unroll
                for (int r = 0; r < 4; ++r)
                    Pl[wid][m * 16 + g * 4 + r][nf * 16 + c] = f2b(sa[m][nf][r]);
        asm volatile("s_waitcnt lgkmcnt(0)" ::: "memory");
#pragma unroll
        for (int ks = 0; ks < 2; ++ks) {
            bf16x8 pa0 = *(const bf16x8*)&Pl[wid][c][ks * 32 + g * 8];
            bf16x8 pa1 = *(const bf16x8*)&Pl[wid][16 + c][ks * 32 + g * 8];
#pragma unroll
            for (int df = 0; df < 8; ++df) {
                bf16x8 vb = *(const bf16x8*)(vh + (size_t)(df * 16 + c) * SQ + kv0 + ks * 32 + g * 8);
                o[0][df] = MFMA16(pa0, vb, o[0][df]);
                o[1][df] = MFMA16(pa1, vb, o[1][df]);
            }
        }
    }
    float inv[2][4];
#pragma unroll
    for (int m = 0; m < 2; ++m)
#pragma unroll
        for (int r = 0; r < 4; ++r) inv[m][r] = 1.f / lrow[m][r];
#pragma unroll
    for (int m = 0; m < 2; ++m)
#pragma unroll
        for (int df = 0; df < 8; ++df)
#pragma unroll
            for (int r = 0; r < 4; ++r) {
                size_t row = qrow0 + m * 16 + g * 4 + r;
                aout[row * QD + h * HD + df * 16 + c] = f2b(o[m][df][r] * inv[m][r]);
            }
}

// ---------------------------------------------------------------------------
extern "C" void kernel_launch(void* const* d_in, const int* in_sizes, int n_in,
                              void* d_out, int out_size, void* d_ws, size_t ws_size,
                              hipStream_t stream) {
    const int*   positions = (const int*)d_in[0];
    const float* hidden    = (const float*)d_in[1];
    const float* wq        = (const float*)d_in[2];
    const float* bq        = (const float*)d_in[3];
    const float* wk        = (const float*)d_in[4];
    const float* bk        = (const float*)d_in[5];
    const float* wv        = (const float*)d_in[6];
    const float* bv        = (const float*)d_in[7];
    const float* wo        = (const float*)d_in[8];
    const float* bo        = (const float*)d_in[9];
    const float* qnw       = (const float*)d_in[10];
    const float* knw       = (const float*)d_in[11];
    float* out = (float*)d_out;

    char* w = (char*)d_ws;
    unsigned short* hidden_b = (unsigned short*)(w);                 // 16 MB
    unsigned short* wq_b     = (unsigned short*)(w + 16777216);      //  8 MB
    unsigned short* wk_b     = (unsigned short*)(w + 25165824);      //  4 MB
    unsigned short* wv_b     = (unsigned short*)(w + 29360128);      //  4 MB
    unsigned short* wo_b     = (unsigned short*)(w + 33554432);      //  8 MB
    unsigned short* qproj    = (unsigned short*)(w + 41943040);      // 16 MB (aliased as attn out)
    unsigned short* kproj    = (unsigned short*)(w + 58720256);      //  8 MB
    unsigned short* q_t      = (unsigned short*)(w + 67108864);      // 16 MB
    unsigned short* k_t      = (unsigned short*)(w + 83886080);      //  8 MB
    unsigned short* v_t      = (unsigned short*)(w + 92274688);      //  8 MB
    float*          cosT     = (float*)(w + 100663296);              //  1 MB
    float*          sinT     = (float*)(w + 101711872);              //  1 MB
    unsigned short* attn     = qproj;  // reuse (qproj consumed before fattn)

    // 1. converts
    cvt_f32_bf16<<<8192, 256, 0, stream>>>(hidden, hidden_b, SQ * HIDN / 4);
    cvt_f32_bf16<<<4096, 256, 0, stream>>>(wq, wq_b, QD * HIDN / 4);
    cvt_f32_bf16<<<2048, 256, 0, stream>>>(wk, wk_b, KD * HIDN / 4);
    cvt_f32_bf16<<<2048, 256, 0, stream>>>(wv, wv_b, KD * HIDN / 4);
    cvt_f32_bf16<<<4096, 256, 0, stream>>>(wo, wo_b, QD * HIDN / 4);
    // 2. rope table
    rope_table<<<SQ * 64 / 256, 256, 0, stream>>>(positions, cosT, sinT);
    // 3. projections
    gemm128<0><<<dim3(QD / 128, SQ / 128), 256, 0, stream>>>(hidden_b, wq_b, bq, qproj, SQ, QD, HIDN);
    gemm128<0><<<dim3(KD / 128, SQ / 128), 256, 0, stream>>>(hidden_b, wk_b, bk, kproj, SQ, KD, HIDN);
    gemm128<2><<<dim3(KD / 128, SQ / 128), 256, 0, stream>>>(hidden_b, wv_b, bv, v_t, SQ, KD, HIDN);
    // 4. norm + rope (q pre-scaled by 1/sqrt(D))
    norm_rope<<<SQ * NH / 4, 256, 0, stream>>>(qproj, NH, qnw, cosT, sinT, q_t, 0.08838834764831845f);
    norm_rope<<<SQ * NKV / 4, 256, 0, stream>>>(kproj, NKV, knw, cosT, sinT, k_t, 1.0f);
    // 5. attention
    fattn<<<dim3(SQ / 128, NH), 256, 0, stream>>>(q_t, k_t, v_t, attn);
    // 6. output projection (f32 out)
    gemm128<1><<<dim3(QD / 128, SQ / 128), 256, 0, stream>>>(attn, wo_b, bo, out, SQ, QD, HIDN);
}

// Round 2
// 540.809 us; speedup vs baseline: 2.3927x; 2.3927x over previous
//
#include <hip/hip_runtime.h>
#include <hip/hip_bf16.h>

#define SQ   4096
#define HIDN 2048
#define NH   16
#define NKV  8
#define HD   128
#define QD   2048   // NH*HD
#define KD   1024   // NKV*HD
#define KVB  64

typedef __bf16 bf16x8 __attribute__((ext_vector_type(8)));
typedef float  f32x4  __attribute__((ext_vector_type(4)));

__device__ __forceinline__ float b2f(unsigned short u) {
    union { float f; unsigned int i; } v; v.i = ((unsigned int)u) << 16; return v.f;
}
__device__ __forceinline__ unsigned short f2b(float f) {
    union { float f; unsigned int i; } v; v.f = f;
    unsigned int i = v.i;
    return (unsigned short)((i + 0x7FFFu + ((i >> 16) & 1u)) >> 16);
}

__device__ __forceinline__ void gload_lds16(const void* g, void* l) {
    __builtin_amdgcn_global_load_lds(
        (const __attribute__((address_space(1))) unsigned int*)g,
        (__attribute__((address_space(3))) unsigned int*)l, 16, 0, 0);
}

#define MFMA16(a, b, c) __builtin_amdgcn_mfma_f32_16x16x32_bf16(a, b, c, 0, 0, 0)

// ---------------------------------------------------------------------------
// f32 -> bf16 convert (vectorized)
// ---------------------------------------------------------------------------
__global__ __launch_bounds__(256) void cvt_f32_bf16(const float* __restrict__ in,
                                                    unsigned short* __restrict__ out,
                                                    int n4) {
    int i = blockIdx.x * 256 + threadIdx.x;
    if (i < n4) {
        float4 v = ((const float4*)in)[i];
        ushort4 u;
        u.x = f2b(v.x); u.y = f2b(v.y); u.z = f2b(v.z); u.w = f2b(v.w);
        ((ushort4*)out)[i] = u;
    }
}

// ---------------------------------------------------------------------------
// RoPE cos/sin table: [S][64] each
// ---------------------------------------------------------------------------
__global__ __launch_bounds__(256) void rope_table(const int* __restrict__ pos,
                                                  float* __restrict__ cosT,
                                                  float* __restrict__ sinT) {
    int i = blockIdx.x * 256 + threadIdx.x;  // S*64 total
    int s = i >> 6, j = i & 63;
    double invf = exp(-(double)j * (log(1.0e6) / 64.0));
    float a = (float)((double)pos[s] * invf);
    cosT[i] = cosf(a);
    sinT[i] = sinf(a);
}

// ---------------------------------------------------------------------------
// GEMM: C[M][N] = A[M][K] @ B[N][K]^T + bias   (A,B bf16; 128x128 tile)
// EPI 0: bf16 row-major   EPI 1: f32 row-major   EPI 2: bf16 transposed C[N][M]
// ---------------------------------------------------------------------------
template <int EPI>
__global__ __launch_bounds__(256) void gemm128(const unsigned short* __restrict__ A,
                                               const unsigned short* __restrict__ B,
                                               const float* __restrict__ bias,
                                               void* __restrict__ Cout,
                                               int M, int N, int K) {
    __shared__ unsigned short As[128 * 32];
    __shared__ unsigned short Bs[128 * 32];
    const int tid = threadIdx.x, wid = tid >> 6, lane = tid & 63;
    const int g = lane >> 4, c = lane & 15;
    const int wr = wid >> 1, wc = wid & 1;
    const long rowbase = (long)blockIdx.y * 128;
    const long colbase = (long)blockIdx.x * 128;

    f32x4 acc[4][4];
#pragma unroll
    for (int m = 0; m < 4; ++m)
#pragma unroll
        for (int n = 0; n < 4; ++n) acc[m][n] = (f32x4){0.f, 0.f, 0.f, 0.f};

    const int ch0 = (wid * 2) * 64 + lane;
    const int ch1 = (wid * 2 + 1) * 64 + lane;

    for (int kt = 0; kt < K; kt += 32) {
        gload_lds16(A + ((rowbase + (ch0 >> 2)) * K + kt + (ch0 & 3) * 8),
                    As + (wid * 2) * 64 * 8);
        gload_lds16(B + ((colbase + (ch0 >> 2)) * K + kt + (ch0 & 3) * 8),
                    Bs + (wid * 2) * 64 * 8);
        gload_lds16(A + ((rowbase + (ch1 >> 2)) * K + kt + (ch1 & 3) * 8),
                    As + (wid * 2 + 1) * 64 * 8);
        gload_lds16(B + ((colbase + (ch1 >> 2)) * K + kt + (ch1 & 3) * 8),
                    Bs + (wid * 2 + 1) * 64 * 8);
        __syncthreads();
        bf16x8 a[4], b[4];
#pragma unroll
        for (int m = 0; m < 4; ++m)
            a[m] = *(const bf16x8*)(As + (wr * 64 + m * 16 + c) * 32 + g * 8);
#pragma unroll
        for (int n = 0; n < 4; ++n)
            b[n] = *(const bf16x8*)(Bs + (wc * 64 + n * 16 + c) * 32 + g * 8);
#pragma unroll
        for (int m = 0; m < 4; ++m)
#pragma unroll
            for (int n = 0; n < 4; ++n) acc[m][n] = MFMA16(a[m], b[n], acc[m][n]);
        __syncthreads();
    }

#pragma unroll
    for (int m = 0; m < 4; ++m) {
        const long grow0 = rowbase + wr * 64 + m * 16 + g * 4;
#pragma unroll
        for (int n = 0; n < 4; ++n) {
            const long gcol = colbase + wc * 64 + n * 16 + c;
            const float bs = bias[gcol];
            if (EPI == 0) {
                unsigned short* C = (unsigned short*)Cout;
#pragma unroll
                for (int r = 0; r < 4; ++r)
                    C[(grow0 + r) * N + gcol] = f2b(acc[m][n][r] + bs);
            } else if (EPI == 1) {
                float* C = (float*)Cout;
#pragma unroll
                for (int r = 0; r < 4; ++r)
                    C[(grow0 + r) * N + gcol] = acc[m][n][r] + bs;
            } else {
                unsigned short* C = (unsigned short*)Cout;
                ushort4 pk;
                pk.x = f2b(acc[m][n][0] + bs);
                pk.y = f2b(acc[m][n][1] + bs);
                pk.z = f2b(acc[m][n][2] + bs);
                pk.w = f2b(acc[m][n][3] + bs);
                *(ushort4*)(C + gcol * (long)M + grow0) = pk;
            }
        }
    }
}

// ---------------------------------------------------------------------------
// RMSNorm + RoPE + transpose to head-major [nh][S][HD]; one wave per (s,h)
// ---------------------------------------------------------------------------
__global__ __launch_bounds__(256) void norm_rope(const unsigned short* __restrict__ proj,
                                                 int nh,
                                                 const float* __restrict__ w,
                                                 const float* __restrict__ cosT,
                                                 const float* __restrict__ sinT,
                                                 unsigned short* __restrict__ outt,
                                                 float oscale) {
    int wv = (blockIdx.x * 256 + threadIdx.x) >> 6;  // over S*nh
    int lane = threadIdx.x & 63;
    int s = wv / nh, h = wv - s * nh;
    const unsigned short* p = proj + (size_t)s * (nh * HD) + h * HD;
    float x1 = b2f(p[lane]);
    float x2 = b2f(p[lane + 64]);
    float ss = x1 * x1 + x2 * x2;
#pragma unroll
    for (int d = 1; d < 64; d <<= 1) ss += __shfl_xor(ss, d);
    float r = rsqrtf(ss * (1.f / 128.f) + 1e-6f);
    x1 *= r * w[lane];
    x2 *= r * w[lane + 64];
    float cs = cosT[s * 64 + lane], sn = sinT[s * 64 + lane];
    unsigned short o1 = f2b((x1 * cs - x2 * sn) * oscale);
    unsigned short o2 = f2b((x2 * cs + x1 * sn) * oscale);
    unsigned short* q = outt + ((size_t)h * SQ + s) * HD;
    q[lane] = o1;
    q[lane + 64] = o2;
}

// ---------------------------------------------------------------------------
// Causal flash attention, LDS-staged K/V, double-buffered.
// qt: [NH][S][HD] (pre-scaled), kt: [NKV][S][HD], vt: [NKV][HD][S] (d-major)
// aout: [S][QD] bf16.
// Grid: 512 blocks 1-D, id -> (qb = 31 - id/16 : longest first, h = id%16).
// Block: 8 waves x 16 q-rows = 128 q-rows. KV tile 64.
// K LDS tile [64][128] bf16 (16KB), V LDS tile [128][64] bf16 (16KB), both
// double-buffered, both XOR-swizzled: phys_byte = logical ^ ((row&7)<<4),
// staged via inverse-swizzled global source (rule: both-sides-or-neither).
// ---------------------------------------------------------------------------
__global__ __launch_bounds__(512) void fattn(const unsigned short* __restrict__ qt,
                                             const unsigned short* __restrict__ kt,
                                             const unsigned short* __restrict__ vt,
                                             unsigned short* __restrict__ aout) {
    __shared__ unsigned short Ks[2][8192];   // [64 s][128 d], swizzled
    __shared__ unsigned short Vs[2][8192];   // [128 d][64 s], swizzled
    __shared__ unsigned short Pl[8][16][72];
    const int tid = threadIdx.x, wid = tid >> 6, lane = tid & 63;
    const int g = lane >> 4, c = lane & 15;
    const int id = blockIdx.x;
    const int qb = 31 - (id >> 4);        // longest blocks dispatched first
    const int h = id & 15, hk = h >> 1;
    const int qrow0 = qb * 128 + wid * 16;
    const unsigned short* qh = qt + (size_t)h * SQ * HD;
    const unsigned short* kh = kt + (size_t)hk * SQ * HD;
    const unsigned short* vh = vt + (size_t)hk * HD * SQ;
    const int ntile = 2 * qb + 2;

    // Q fragments (16 rows per wave), pre-scaled by 1/sqrt(D)
    bf16x8 qa[4];
#pragma unroll
    for (int ks = 0; ks < 4; ++ks)
        qa[ks] = *(const bf16x8*)(qh + (size_t)(qrow0 + c) * HD + ks * 32 + g * 8);

    f32x4 o[8];
#pragma unroll
    for (int df = 0; df < 8; ++df) o[df] = (f32x4){0.f, 0.f, 0.f, 0.f};
    float mrow[4], lrow[4];
#pragma unroll
    for (int r = 0; r < 4; ++r) { mrow[r] = -1e30f; lrow[r] = 0.f; }

    // ---- staging: tile t into buffer b (all 8 waves, 2 KB each of K and V)
    auto stage = [&](int b, int t) {
        const int kv0 = t * KVB;
#pragma unroll
        for (int i = 0; i < 2; ++i) {
            const int gi = wid * 2 + i;          // 1KB granule group 0..15
            const int P = gi * 1024 + lane * 16; // this lane's phys byte
            // K: phys row = P>>8 (256B rows); logical U = P ^ ((row&7)<<4)
            const int rk = P >> 8;
            const int Uk = P ^ ((rk & 7) << 4);
            gload_lds16(kh + (size_t)(kv0 + rk) * HD + ((Uk & 255) >> 1),
                        (char*)Ks[b] + gi * 1024);
            // V: phys row = P>>7 (128B rows)
            const int rv = P >> 7;
            const int Uv = P ^ ((rv & 7) << 4);
            gload_lds16(vh + (size_t)rv * SQ + kv0 + ((Uv & 127) >> 1),
                        (char*)Vs[b] + gi * 1024);
        }
    };

    stage(0, 0);
    asm volatile("s_waitcnt vmcnt(0)" ::: "memory");
    __syncthreads();

    int bcur = 0;
    for (int j = 0; j < ntile; ++j) {
        const int kv0 = j * KVB;
        if (j + 1 < ntile) stage(bcur ^ 1, j + 1);

        if (kv0 <= qrow0 + 15) {  // wave has unmasked work in this tile
            // ---- QK^T
            f32x4 sa[4];
#pragma unroll
            for (int nf = 0; nf < 4; ++nf) sa[nf] = (f32x4){0.f, 0.f, 0.f, 0.f};
#pragma unroll
            for (int nf = 0; nf < 4; ++nf) {
                const int row = nf * 16 + c;
#pragma unroll
                for (int ks = 0; ks < 4; ++ks) {
                    const int ph = row * 256 + ((ks * 64 + g * 16) ^ ((row & 7) << 4));
                    bf16x8 kf = *(const bf16x8*)((const char*)Ks[bcur] + ph);
                    sa[nf] = MFMA16(qa[ks], kf, sa[nf]);
                }
            }
            // ---- causal mask
            if (kv0 + 63 > qrow0) {
#pragma unroll
                for (int nf = 0; nf < 4; ++nf)
#pragma unroll
                    for (int r = 0; r < 4; ++r) {
                        int row = qrow0 + g * 4 + r;
                        int col = kv0 + nf * 16 + c;
                        if (col > row) sa[nf][r] = -1e30f;
                    }
            }
            // ---- online softmax (reduce over 16 c-lanes)
            float psc[4];
#pragma unroll
            for (int r = 0; r < 4; ++r) {
                float mx = fmaxf(fmaxf(sa[0][r], sa[1][r]), fmaxf(sa[2][r], sa[3][r]));
                mx = fmaxf(mx, __shfl_xor(mx, 1));
                mx = fmaxf(mx, __shfl_xor(mx, 2));
                mx = fmaxf(mx, __shfl_xor(mx, 4));
                mx = fmaxf(mx, __shfl_xor(mx, 8));
                float mn = fmaxf(mrow[r], mx);
                float sc = __expf(mrow[r] - mn);
                mrow[r] = mn;
                float rs = 0.f;
#pragma unroll
                for (int nf = 0; nf < 4; ++nf) {
                    float p = __expf(sa[nf][r] - mn);
                    sa[nf][r] = p;
                    rs += p;
                }
                rs += __shfl_xor(rs, 1);
                rs += __shfl_xor(rs, 2);
                rs += __shfl_xor(rs, 4);
                rs += __shfl_xor(rs, 8);
                lrow[r] = lrow[r] * sc + rs;
                psc[r] = sc;
            }
#pragma unroll
            for (int df = 0; df < 8; ++df)
#pragma unroll
                for (int r = 0; r < 4; ++r) o[df][r] *= psc[r];
            // ---- P -> LDS (re-layout for PV A-operand)
#pragma unroll
            for (int nf = 0; nf < 4; ++nf)
#pragma unroll
                for (int r = 0; r < 4; ++r)
                    Pl[wid][g * 4 + r][nf * 16 + c] = f2b(sa[nf][r]);
            asm volatile("s_waitcnt lgkmcnt(0)" ::: "memory");
            // ---- PV
#pragma unroll
            for (int ks = 0; ks < 2; ++ks) {
                bf16x8 pa = *(const bf16x8*)&Pl[wid][c][ks * 32 + g * 8];
#pragma unroll
                for (int df = 0; df < 8; ++df) {
                    const int rd = df * 16 + c;
                    const int ph = rd * 128 + ((ks * 64 + g * 16) ^ ((rd & 7) << 4));
                    bf16x8 vb = *(const bf16x8*)((const char*)Vs[bcur] + ph);
                    o[df] = MFMA16(pa, vb, o[df]);
                }
            }
        }
        __syncthreads();  // drains vmcnt(0) (staging) + lgkm; all waves done with bcur
        bcur ^= 1;
    }

    float inv[4];
#pragma unroll
    for (int r = 0; r < 4; ++r) inv[r] = 1.f / lrow[r];
#pragma unroll
    for (int df = 0; df < 8; ++df)
#pragma unroll
        for (int r = 0; r < 4; ++r) {
            size_t row = qrow0 + g * 4 + r;
            aout[row * QD + h * HD + df * 16 + c] = f2b(o[df][r] * inv[r]);
        }
}

// ---------------------------------------------------------------------------
extern "C" void kernel_launch(void* const* d_in, const int* in_sizes, int n_in,
                              void* d_out, int out_size, void* d_ws, size_t ws_size,
                              hipStream_t stream) {
    const int*   positions = (const int*)d_in[0];
    const float* hidden    = (const float*)d_in[1];
    const float* wq        = (const float*)d_in[2];
    const float* bq        = (const float*)d_in[3];
    const float* wk        = (const float*)d_in[4];
    const float* bk        = (const float*)d_in[5];
    const float* wv        = (const float*)d_in[6];
    const float* bv        = (const float*)d_in[7];
    const float* wo        = (const float*)d_in[8];
    const float* bo        = (const float*)d_in[9];
    const float* qnw       = (const float*)d_in[10];
    const float* knw       = (const float*)d_in[11];
    float* out = (float*)d_out;

    char* w = (char*)d_ws;
    unsigned short* hidden_b = (unsigned short*)(w);                 // 16 MB
    unsigned short* wq_b     = (unsigned short*)(w + 16777216);      //  8 MB
    unsigned short* wk_b     = (unsigned short*)(w + 25165824);      //  4 MB
    unsigned short* wv_b     = (unsigned short*)(w + 29360128);      //  4 MB
    unsigned short* wo_b     = (unsigned short*)(w + 33554432);      //  8 MB
    unsigned short* qproj    = (unsigned short*)(w + 41943040);      // 16 MB (aliased as attn out)
    unsigned short* kproj    = (unsigned short*)(w + 58720256);      //  8 MB
    unsigned short* q_t      = (unsigned short*)(w + 67108864);      // 16 MB
    unsigned short* k_t      = (unsigned short*)(w + 83886080);      //  8 MB
    unsigned short* v_t      = (unsigned short*)(w + 92274688);      //  8 MB
    float*          cosT     = (float*)(w + 100663296);              //  1 MB
    float*          sinT     = (float*)(w + 101711872);              //  1 MB
    unsigned short* attn     = qproj;  // reuse (qproj consumed before fattn)

    // 1. converts
    cvt_f32_bf16<<<8192, 256, 0, stream>>>(hidden, hidden_b, SQ * HIDN / 4);
    cvt_f32_bf16<<<4096, 256, 0, stream>>>(wq, wq_b, QD * HIDN / 4);
    cvt_f32_bf16<<<2048, 256, 0, stream>>>(wk, wk_b, KD * HIDN / 4);
    cvt_f32_bf16<<<2048, 256, 0, stream>>>(wv, wv_b, KD * HIDN / 4);
    cvt_f32_bf16<<<4096, 256, 0, stream>>>(wo, wo_b, QD * HIDN / 4);
    // 2. rope table
    rope_table<<<SQ * 64 / 256, 256, 0, stream>>>(positions, cosT, sinT);
    // 3. projections
    gemm128<0><<<dim3(QD / 128, SQ / 128), 256, 0, stream>>>(hidden_b, wq_b, bq, qproj, SQ, QD, HIDN);
    gemm128<0><<<dim3(KD / 128, SQ / 128), 256, 0, stream>>>(hidden_b, wk_b, bk, kproj, SQ, KD, HIDN);
    gemm128<2><<<dim3(KD / 128, SQ / 128), 256, 0, stream>>>(hidden_b, wv_b, bv, v_t, SQ, KD, HIDN);
    // 4. norm + rope (q pre-scaled by 1/sqrt(D))
    norm_rope<<<SQ * NH / 4, 256, 0, stream>>>(qproj, NH, qnw, cosT, sinT, q_t, 0.08838834764831845f);
    norm_rope<<<SQ * NKV / 4, 256, 0, stream>>>(kproj, NKV, knw, cosT, sinT, k_t, 1.0f);
    // 5. attention
    fattn<<<512, 512, 0, stream>>>(q_t, k_t, v_t, attn);
    // 6. output projection (f32 out)
    gemm128<1><<<dim3(QD / 128, SQ / 128), 256, 0, stream>>>(attn, wo_b, bo, out, SQ, QD, HIDN);
}

// Round 3
// 517.208 us; speedup vs baseline: 2.5019x; 1.0456x over previous
//
#include <hip/hip_runtime.h>
#include <hip/hip_bf16.h>

#define SQ   4096
#define HIDN 2048
#define NH   16
#define NKV  8
#define HD   128
#define QD   2048   // NH*HD
#define KD   1024   // NKV*HD
#define KVB  64

typedef __bf16 bf16x8 __attribute__((ext_vector_type(8)));
typedef float  f32x4  __attribute__((ext_vector_type(4)));

__device__ __forceinline__ float b2f(unsigned short u) {
    union { float f; unsigned int i; } v; v.i = ((unsigned int)u) << 16; return v.f;
}
__device__ __forceinline__ unsigned short f2b(float f) {
    union { float f; unsigned int i; } v; v.f = f;
    unsigned int i = v.i;
    return (unsigned short)((i + 0x7FFFu + ((i >> 16) & 1u)) >> 16);
}

__device__ __forceinline__ void gload_lds16(const void* g, void* l) {
    __builtin_amdgcn_global_load_lds(
        (const __attribute__((address_space(1))) unsigned int*)g,
        (__attribute__((address_space(3))) unsigned int*)l, 16, 0, 0);
}

#define MFMA16(a, b, c) __builtin_amdgcn_mfma_f32_16x16x32_bf16(a, b, c, 0, 0, 0)

// DPP row-rotate (within 16-lane rows) for cross-lane reduce on the VALU pipe.
#define DPP_ROR(x, n) __int_as_float(__builtin_amdgcn_update_dpp(            \
    __float_as_int(x), __float_as_int(x), 0x120 + (n), 0xF, 0xF, false))

__device__ __forceinline__ float rowmax16(float x) {
    x = fmaxf(x, DPP_ROR(x, 1));
    x = fmaxf(x, DPP_ROR(x, 2));
    x = fmaxf(x, DPP_ROR(x, 4));
    x = fmaxf(x, DPP_ROR(x, 8));
    return x;
}
__device__ __forceinline__ float rowsum16(float x) {
    x += DPP_ROR(x, 1);
    x += DPP_ROR(x, 2);
    x += DPP_ROR(x, 4);
    x += DPP_ROR(x, 8);
    return x;
}

// ---------------------------------------------------------------------------
// merged f32 -> bf16 convert for all 5 tensors (one launch)
// ---------------------------------------------------------------------------
__global__ __launch_bounds__(256) void cvt_all(const float* __restrict__ h,
                                               const float* __restrict__ wq,
                                               const float* __restrict__ wk,
                                               const float* __restrict__ wv,
                                               const float* __restrict__ wo,
                                               unsigned short* __restrict__ oh,
                                               unsigned short* __restrict__ owq,
                                               unsigned short* __restrict__ owk,
                                               unsigned short* __restrict__ owv,
                                               unsigned short* __restrict__ owo) {
    int i = blockIdx.x * 256 + threadIdx.x;  // float4 index, 5M total
    const float* src; unsigned short* dst; int off;
    if (i < 2097152)      { src = h;  dst = oh;  off = i; }
    else if (i < 3145728) { src = wq; dst = owq; off = i - 2097152; }
    else if (i < 3670016) { src = wk; dst = owk; off = i - 3145728; }
    else if (i < 4194304) { src = wv; dst = owv; off = i - 3670016; }
    else                  { src = wo; dst = owo; off = i - 4194304; }
    float4 v = ((const float4*)src)[off];
    ushort4 u;
    u.x = f2b(v.x); u.y = f2b(v.y); u.z = f2b(v.z); u.w = f2b(v.w);
    ((ushort4*)dst)[off] = u;
}

// ---------------------------------------------------------------------------
// RoPE cos/sin table: [S][64] each
// ---------------------------------------------------------------------------
__global__ __launch_bounds__(256) void rope_table(const int* __restrict__ pos,
                                                  float* __restrict__ cosT,
                                                  float* __restrict__ sinT) {
    int i = blockIdx.x * 256 + threadIdx.x;  // S*64 total
    int s = i >> 6, j = i & 63;
    double invf = exp(-(double)j * (log(1.0e6) / 64.0));
    float a = (float)((double)pos[s] * invf);
    cosT[i] = cosf(a);
    sinT[i] = sinf(a);
}

// ---------------------------------------------------------------------------
// GEMM: C[M][N] = A[M][K] @ B[N][K]^T + bias   (A,B bf16; 128x128 tile)
// EPI 0: bf16 row-major   EPI 1: f32 row-major   EPI 2: bf16 transposed C[N][M]
// XCD-bijective block swizzle (nwg % 8 == 0 for all our grids).
// ---------------------------------------------------------------------------
template <int EPI>
__global__ __launch_bounds__(256) void gemm128(const unsigned short* __restrict__ A,
                                               const unsigned short* __restrict__ B,
                                               const float* __restrict__ bias,
                                               void* __restrict__ Cout,
                                               int M, int N, int K) {
    __shared__ unsigned short As[128 * 32];
    __shared__ unsigned short Bs[128 * 32];
    const int tid = threadIdx.x, wid = tid >> 6, lane = tid & 63;
    const int g = lane >> 4, c = lane & 15;
    const int wr = wid >> 1, wc = wid & 1;
    // XCD swizzle: hardware round-robins orig%8 across XCDs; give each XCD a
    // contiguous chunk of work tiles so A-panels stay in its L2.
    const int orig = blockIdx.y * gridDim.x + blockIdx.x;
    const int cpx = (gridDim.x * gridDim.y) >> 3;
    const int wg = (orig & 7) * cpx + (orig >> 3);
    const int bx = wg % gridDim.x, by = wg / gridDim.x;
    const long rowbase = (long)by * 128;
    const long colbase = (long)bx * 128;

    f32x4 acc[4][4];
#pragma unroll
    for (int m = 0; m < 4; ++m)
#pragma unroll
        for (int n = 0; n < 4; ++n) acc[m][n] = (f32x4){0.f, 0.f, 0.f, 0.f};

    const int ch0 = (wid * 2) * 64 + lane;
    const int ch1 = (wid * 2 + 1) * 64 + lane;

    for (int kt = 0; kt < K; kt += 32) {
        gload_lds16(A + ((rowbase + (ch0 >> 2)) * K + kt + (ch0 & 3) * 8),
                    As + (wid * 2) * 64 * 8);
        gload_lds16(B + ((colbase + (ch0 >> 2)) * K + kt + (ch0 & 3) * 8),
                    Bs + (wid * 2) * 64 * 8);
        gload_lds16(A + ((rowbase + (ch1 >> 2)) * K + kt + (ch1 & 3) * 8),
                    As + (wid * 2 + 1) * 64 * 8);
        gload_lds16(B + ((colbase + (ch1 >> 2)) * K + kt + (ch1 & 3) * 8),
                    Bs + (wid * 2 + 1) * 64 * 8);
        __syncthreads();
        bf16x8 a[4], b[4];
#pragma unroll
        for (int m = 0; m < 4; ++m)
            a[m] = *(const bf16x8*)(As + (wr * 64 + m * 16 + c) * 32 + g * 8);
#pragma unroll
        for (int n = 0; n < 4; ++n)
            b[n] = *(const bf16x8*)(Bs + (wc * 64 + n * 16 + c) * 32 + g * 8);
#pragma unroll
        for (int m = 0; m < 4; ++m)
#pragma unroll
            for (int n = 0; n < 4; ++n) acc[m][n] = MFMA16(a[m], b[n], acc[m][n]);
        __syncthreads();
    }

#pragma unroll
    for (int m = 0; m < 4; ++m) {
        const long grow0 = rowbase + wr * 64 + m * 16 + g * 4;
#pragma unroll
        for (int n = 0; n < 4; ++n) {
            const long gcol = colbase + wc * 64 + n * 16 + c;
            const float bs = bias[gcol];
            if (EPI == 0) {
                unsigned short* C = (unsigned short*)Cout;
#pragma unroll
                for (int r = 0; r < 4; ++r)
                    C[(grow0 + r) * N + gcol] = f2b(acc[m][n][r] + bs);
            } else if (EPI == 1) {
                float* C = (float*)Cout;
#pragma unroll
                for (int r = 0; r < 4; ++r)
                    C[(grow0 + r) * N + gcol] = acc[m][n][r] + bs;
            } else {
                unsigned short* C = (unsigned short*)Cout;
                ushort4 pk;
                pk.x = f2b(acc[m][n][0] + bs);
                pk.y = f2b(acc[m][n][1] + bs);
                pk.z = f2b(acc[m][n][2] + bs);
                pk.w = f2b(acc[m][n][3] + bs);
                *(ushort4*)(C + gcol * (long)M + grow0) = pk;
            }
        }
    }
}

// ---------------------------------------------------------------------------
// RMSNorm + RoPE + transpose to head-major [nh][S][HD]; one wave per (s,h)
// ---------------------------------------------------------------------------
__global__ __launch_bounds__(256) void norm_rope(const unsigned short* __restrict__ proj,
                                                 int nh,
                                                 const float* __restrict__ w,
                                                 const float* __restrict__ cosT,
                                                 const float* __restrict__ sinT,
                                                 unsigned short* __restrict__ outt,
                                                 float oscale) {
    int wv = (blockIdx.x * 256 + threadIdx.x) >> 6;  // over S*nh
    int lane = threadIdx.x & 63;
    int s = wv / nh, h = wv - s * nh;
    const unsigned short* p = proj + (size_t)s * (nh * HD) + h * HD;
    float x1 = b2f(p[lane]);
    float x2 = b2f(p[lane + 64]);
    float ss = x1 * x1 + x2 * x2;
#pragma unroll
    for (int d = 1; d < 64; d <<= 1) ss += __shfl_xor(ss, d);
    float r = rsqrtf(ss * (1.f / 128.f) + 1e-6f);
    x1 *= r * w[lane];
    x2 *= r * w[lane + 64];
    float cs = cosT[s * 64 + lane], sn = sinT[s * 64 + lane];
    unsigned short o1 = f2b((x1 * cs - x2 * sn) * oscale);
    unsigned short o2 = f2b((x2 * cs + x1 * sn) * oscale);
    unsigned short* q = outt + ((size_t)h * SQ + s) * HD;
    q[lane] = o1;
    q[lane + 64] = o2;
}

// ---------------------------------------------------------------------------
// Causal flash attention v3.
// qt: [NH][S][HD] pre-scaled by scale*log2e; kt: [NKV][S][HD]; vt: [NKV][HD][S]
// aout: [S][QD] bf16.
// Block: 4 waves x 32 q-rows = 128 q-rows.  KV tile 64.  LDS 80KB -> 2 blk/CU.
// Grid 512: id<256 -> qb=id>>4, else qb=31-((id-256)>>4); h=id&15.
//   (id and id+256 land on the same CU under XCD round-robin: complementary
//    causal lengths -> balanced, same kv head -> L2 reuse.)
// kv remap: within a tile, fragment nf / lane c covers kv = 4*c+nf so each
// lane's P row-piece is 4 consecutive kv (cvt_pk + ds_write_b64).
// All LDS tiles XOR-swizzled with key derived from row, applied on BOTH the
// pre-swizzled global staging source and the swizzled reads.
// ---------------------------------------------------------------------------
__global__ __launch_bounds__(256, 2) void fattn(const unsigned short* __restrict__ qt,
                                                const unsigned short* __restrict__ kt,
                                                const unsigned short* __restrict__ vt,
                                                unsigned short* __restrict__ aout) {
    __shared__ unsigned short Ks[2][KVB * HD];   // [64 kv][128 d], key=(row>>2)&7
    __shared__ unsigned short Vs[2][HD * KVB];   // [128 d][64 kv], key=row&7
    __shared__ unsigned short Pl[4][32][64];     // per-wave P, key=row&7
    const int tid = threadIdx.x, wid = tid >> 6, lane = tid & 63;
    const int g = lane >> 4, c = lane & 15;
    const int id = blockIdx.x;
    const int qb = (id < 256) ? (id >> 4) : (31 - ((id - 256) >> 4));
    const int h = id & 15, hk = h >> 1;
    const int qrow0 = qb * 128 + wid * 32;
    const unsigned short* qh = qt + (size_t)h * SQ * HD;
    const unsigned short* kh = kt + (size_t)hk * SQ * HD;
    const unsigned short* vh = vt + (size_t)hk * HD * SQ;
    const int ntile = 2 * qb + 2;
    char* plw = (char*)&Pl[wid][0][0];

    // Q fragments: 2 m-blocks of 16 rows
    bf16x8 qa[2][4];
#pragma unroll
    for (int m = 0; m < 2; ++m)
#pragma unroll
        for (int ks = 0; ks < 4; ++ks)
            qa[m][ks] = *(const bf16x8*)(qh + (size_t)(qrow0 + m * 16 + c) * HD + ks * 32 + g * 8);

    f32x4 o[2][8];
#pragma unroll
    for (int m = 0; m < 2; ++m)
#pragma unroll
        for (int df = 0; df < 8; ++df) o[m][df] = (f32x4){0.f, 0.f, 0.f, 0.f};
    float mrow[2][4], lrow[2][4];
#pragma unroll
    for (int m = 0; m < 2; ++m)
#pragma unroll
        for (int r = 0; r < 4; ++r) { mrow[m][r] = -1e30f; lrow[m][r] = 0.f; }

    // staging: 16 x 1KB granules per tensor, wave takes 4 of each
    auto stage = [&](int b, int t) {
        const int kv0 = t * KVB;
#pragma unroll
        for (int i = 0; i < 4; ++i) {
            const int gi = wid * 4 + i;
            const int P = gi * 1024 + lane * 16;
            const int rk = P >> 8;                                  // K row
            const int Uk = (P & 255) ^ (((rk >> 2) & 7) << 4);
            gload_lds16(kh + (size_t)(kv0 + rk) * HD + (Uk >> 1),
                        (char*)Ks[b] + gi * 1024);
            const int rv = P >> 7;                                  // V row (d)
            const int Uv = (P & 127) ^ ((rv & 7) << 4);
            gload_lds16(vh + (size_t)rv * SQ + kv0 + (Uv >> 1),
                        (char*)Vs[b] + gi * 1024);
        }
    };

    stage(0, 0);
    asm volatile("s_waitcnt vmcnt(0)" ::: "memory");
    __syncthreads();

    int bcur = 0;
    for (int j = 0; j < ntile; ++j) {
        const int kv0 = j * KVB;
        if (j + 1 < ntile) stage(bcur ^ 1, j + 1);

        if (kv0 <= qrow0 + 31) {  // wave has unmasked work
            // ---- QK^T (kv = 4*c + nf)
            f32x4 sa[2][4];
#pragma unroll
            for (int m = 0; m < 2; ++m)
#pragma unroll
                for (int nf = 0; nf < 4; ++nf) sa[m][nf] = (f32x4){0.f, 0.f, 0.f, 0.f};
            __builtin_amdgcn_s_setprio(1);
#pragma unroll
            for (int nf = 0; nf < 4; ++nf) {
                const int row = (c << 2) + nf;
                const int key = (c & 7) << 4;  // == ((row>>2)&7)<<4
#pragma unroll
                for (int ks = 0; ks < 4; ++ks) {
                    bf16x8 kf = *(const bf16x8*)((const char*)Ks[bcur] + row * 256 +
                                                 ((ks * 64 + g * 16) ^ key));
                    sa[0][nf] = MFMA16(qa[0][ks], kf, sa[0][nf]);
                    sa[1][nf] = MFMA16(qa[1][ks], kf, sa[1][nf]);
                }
            }
            __builtin_amdgcn_s_setprio(0);
            // ---- causal mask (col = kv0 + 4c + nf)
            if (kv0 + 63 > qrow0) {
#pragma unroll
                for (int m = 0; m < 2; ++m)
#pragma unroll
                    for (int nf = 0; nf < 4; ++nf) {
                        const int col = kv0 + (c << 2) + nf;
#pragma unroll
                        for (int r = 0; r < 4; ++r) {
                            int row = qrow0 + m * 16 + g * 4 + r;
                            if (col > row) sa[m][nf][r] = -1e30f;
                        }
                    }
            }
            // ---- online softmax in exp2 domain, defer-max (T13)
            float nmax[2][4];
            int small = 1;
#pragma unroll
            for (int m = 0; m < 2; ++m)
#pragma unroll
                for (int r = 0; r < 4; ++r) {
                    float mx = fmaxf(fmaxf(sa[m][0][r], sa[m][1][r]),
                                     fmaxf(sa[m][2][r], sa[m][3][r]));
                    mx = rowmax16(mx);
                    nmax[m][r] = mx;
                    small &= (mx <= mrow[m][r] + 8.0f);
                }
            if (!__all(small)) {
                float psc[2][4];
#pragma unroll
                for (int m = 0; m < 2; ++m)
#pragma unroll
                    for (int r = 0; r < 4; ++r) {
                        float mn = fmaxf(mrow[m][r], nmax[m][r]);
                        psc[m][r] = __builtin_amdgcn_exp2f(mrow[m][r] - mn);
                        mrow[m][r] = mn;
                        lrow[m][r] *= psc[m][r];
                    }
#pragma unroll
                for (int m = 0; m < 2; ++m)
#pragma unroll
                    for (int df = 0; df < 8; ++df)
#pragma unroll
                        for (int r = 0; r < 4; ++r) o[m][df][r] *= psc[m][r];
            }
#pragma unroll
            for (int m = 0; m < 2; ++m)
#pragma unroll
                for (int r = 0; r < 4; ++r) {
                    float rs = 0.f;
#pragma unroll
                    for (int nf = 0; nf < 4; ++nf) {
                        float p = __builtin_amdgcn_exp2f(sa[m][nf][r] - mrow[m][r]);
                        sa[m][nf][r] = p;
                        rs += p;
                    }
                    lrow[m][r] += rowsum16(rs);
                }
            // ---- P -> LDS: 4 consecutive kv per lane -> cvt_pk + b64 write
#pragma unroll
            for (int m = 0; m < 2; ++m)
#pragma unroll
                for (int r = 0; r < 4; ++r) {
                    unsigned int lo, hi;
                    asm("v_cvt_pk_bf16_f32 %0, %1, %2"
                        : "=v"(lo) : "v"(sa[m][0][r]), "v"(sa[m][1][r]));
                    asm("v_cvt_pk_bf16_f32 %0, %1, %2"
                        : "=v"(hi) : "v"(sa[m][2][r]), "v"(sa[m][3][r]));
                    const int row = m * 16 + g * 4 + r;
                    const int pcol = (c * 8) ^ ((row & 7) << 4);
                    *(uint2*)(plw + row * 128 + pcol) = make_uint2(lo, hi);
                }
            // ---- PV
            __builtin_amdgcn_s_setprio(1);
#pragma unroll
            for (int ks = 0; ks < 2; ++ks) {
                bf16x8 pa0 = *(const bf16x8*)(plw + (0 * 16 + c) * 128 +
                                              ((ks * 64 + g * 16) ^ ((c & 7) << 4)));
                bf16x8 pa1 = *(const bf16x8*)(plw + (1 * 16 + c) * 128 +
                                              ((ks * 64 + g * 16) ^ ((c & 7) << 4)));
#pragma unroll
                for (int df = 0; df < 8; ++df) {
                    const int rd = df * 16 + c;
                    bf16x8 vb = *(const bf16x8*)((const char*)Vs[bcur] + rd * 128 +
                                                 ((ks * 64 + g * 16) ^ ((rd & 7) << 4)));
                    o[0][df] = MFMA16(pa0, vb, o[0][df]);
                    o[1][df] = MFMA16(pa1, vb, o[1][df]);
                }
            }
            __builtin_amdgcn_s_setprio(0);
        }
        asm volatile("s_waitcnt vmcnt(0)" ::: "memory");
        __syncthreads();
        bcur ^= 1;
    }

    float inv[2][4];
#pragma unroll
    for (int m = 0; m < 2; ++m)
#pragma unroll
        for (int r = 0; r < 4; ++r) inv[m][r] = 1.f / lrow[m][r];
#pragma unroll
    for (int m = 0; m < 2; ++m)
#pragma unroll
        for (int df = 0; df < 8; ++df)
#pragma unroll
            for (int r = 0; r < 4; ++r) {
                size_t row = qrow0 + m * 16 + g * 4 + r;
                aout[row * QD + h * HD + df * 16 + c] = f2b(o[m][df][r] * inv[m][r]);
            }
}

// ---------------------------------------------------------------------------
extern "C" void kernel_launch(void* const* d_in, const int* in_sizes, int n_in,
                              void* d_out, int out_size, void* d_ws, size_t ws_size,
                              hipStream_t stream) {
    const int*   positions = (const int*)d_in[0];
    const float* hidden    = (const float*)d_in[1];
    const float* wq        = (const float*)d_in[2];
    const float* bq        = (const float*)d_in[3];
    const float* wk        = (const float*)d_in[4];
    const float* bk        = (const float*)d_in[5];
    const float* wv        = (const float*)d_in[6];
    const float* bv        = (const float*)d_in[7];
    const float* wo        = (const float*)d_in[8];
    const float* bo        = (const float*)d_in[9];
    const float* qnw       = (const float*)d_in[10];
    const float* knw       = (const float*)d_in[11];
    float* out = (float*)d_out;

    char* w = (char*)d_ws;
    unsigned short* hidden_b = (unsigned short*)(w);                 // 16 MB
    unsigned short* wq_b     = (unsigned short*)(w + 16777216);      //  8 MB
    unsigned short* wk_b     = (unsigned short*)(w + 25165824);      //  4 MB
    unsigned short* wv_b     = (unsigned short*)(w + 29360128);      //  4 MB
    unsigned short* wo_b     = (unsigned short*)(w + 33554432);      //  8 MB
    unsigned short* qproj    = (unsigned short*)(w + 41943040);      // 16 MB (aliased as attn out)
    unsigned short* kproj    = (unsigned short*)(w + 58720256);      //  8 MB
    unsigned short* q_t      = (unsigned short*)(w + 67108864);      // 16 MB
    unsigned short* k_t      = (unsigned short*)(w + 83886080);      //  8 MB
    unsigned short* v_t      = (unsigned short*)(w + 92274688);      //  8 MB
    float*          cosT     = (float*)(w + 100663296);              //  1 MB
    float*          sinT     = (float*)(w + 101711872);              //  1 MB
    unsigned short* attn     = qproj;  // reuse (qproj consumed before fattn)

    // 1. converts (one launch)
    cvt_all<<<20480, 256, 0, stream>>>(hidden, wq, wk, wv, wo,
                                       hidden_b, wq_b, wk_b, wv_b, wo_b);
    // 2. rope table
    rope_table<<<SQ * 64 / 256, 256, 0, stream>>>(positions, cosT, sinT);
    // 3. projections
    gemm128<0><<<dim3(QD / 128, SQ / 128), 256, 0, stream>>>(hidden_b, wq_b, bq, qproj, SQ, QD, HIDN);
    gemm128<0><<<dim3(KD / 128, SQ / 128), 256, 0, stream>>>(hidden_b, wk_b, bk, kproj, SQ, KD, HIDN);
    gemm128<2><<<dim3(KD / 128, SQ / 128), 256, 0, stream>>>(hidden_b, wv_b, bv, v_t, SQ, KD, HIDN);
    // 4. norm + rope (q pre-scaled by 1/sqrt(D) * log2(e) for exp2-domain softmax)
    norm_rope<<<SQ * NH / 4, 256, 0, stream>>>(qproj, NH, qnw, cosT, sinT, q_t,
                                               (float)(0.08838834764831845 * 1.4426950408889634));
    norm_rope<<<SQ * NKV / 4, 256, 0, stream>>>(kproj, NKV, knw, cosT, sinT, k_t, 1.0f);
    // 5. attention
    fattn<<<512, 256, 0, stream>>>(q_t, k_t, v_t, attn);
    // 6. output projection (f32 out)
    gemm128<1><<<dim3(QD / 128, SQ / 128), 256, 0, stream>>>(attn, wo_b, bo, out, SQ, QD, HIDN);
}